// Round 1
// baseline (319.781 us; speedup 1.0000x reference)
//
#include <hip/hip_runtime.h>
#include <cstdint>
#include <cstddef>

// Problem constants (fixed by the reference file)
#define B_SZ  8
#define C_IN  2049          // N_FFT/2+1
#define C2    4098          // 2*C_IN rows of the basis
#define T_FR  345           // MAX_FRAMES
#define NFFT  4096
#define HOPSZ 1024
#define KPAD  4128          // C2 padded to multiple of 32 (BK)
#define MROWS 2760          // B_SZ*T_FR
#define MPAD  2816          // padded to multiple of 128

typedef __bf16 bf16x8 __attribute__((ext_vector_type(8)));
typedef float f32x4 __attribute__((ext_vector_type(4)));

__device__ __forceinline__ unsigned short f2b(float f) {
  union { float f; unsigned int u; } v; v.f = f;
  unsigned int r = v.u + 0x7fffu + ((v.u >> 16) & 1u);  // RNE to bf16
  return (unsigned short)(r >> 16);
}
__device__ __forceinline__ float b2f(unsigned short h) {
  union { unsigned int u; float f; } v; v.u = ((unsigned int)h) << 16;
  return v.f;
}

// ---------------------------------------------------------------------------
// Zero the A + Wt operand region of the workspace (pad rows/cols must be 0;
// harness poisons ws with 0xAA before every launch).
__global__ void zero_ws(uint4* __restrict__ p, int n16) {
  int i = blockIdx.x * 256 + threadIdx.x;
  if (i < n16) p[i] = uint4{0u, 0u, 0u, 0u};
}

// ---------------------------------------------------------------------------
// Build A[m, k] (bf16, [MPAD x KPAD], row-major, k-contiguous) from
// real/imag [B, C_IN, T_FR].  mag*cos(atan2(i, r+eps)) = mag*(r+eps)/hyp etc.
// LDS tile transpose: read t-contiguous, write k-contiguous.
__global__ void build_A(const float* __restrict__ re, const float* __restrict__ im,
                        unsigned short* __restrict__ A) {
  __shared__ float tr[64][65];
  __shared__ float ti[64][65];
  const int tid = threadIdx.x;
  const int t0 = blockIdx.x * 64;
  const int c0 = blockIdx.y * 64;
  const int b  = blockIdx.z;
#pragma unroll
  for (int pass = 0; pass < 16; ++pass) {
    int idx = pass * 256 + tid;
    int tt = idx & 63, cc = idx >> 6;
    int c = c0 + cc, t = t0 + tt;
    float rp = 0.f, ip = 0.f;
    if (c < C_IN && t < T_FR) {
      size_t off = ((size_t)b * C_IN + c) * T_FR + t;
      float r = re[off], i = im[off];
      float x   = r + 1.1920929e-7f;           // real + eps (phase arg)
      float mag = sqrtf(r * r + i * i);
      float h2  = sqrtf(x * x + i * i);
      float inv = (h2 > 0.f) ? (mag / h2) : 0.f;
      rp = x * inv;                             // mag*cos(phase)
      ip = i * inv;                             // mag*sin(phase)
    }
    tr[cc][tt] = rp;
    ti[cc][tt] = ip;
  }
  __syncthreads();
#pragma unroll
  for (int pass = 0; pass < 16; ++pass) {
    int idx = pass * 256 + tid;
    int kk = idx & 63, tt = idx >> 6;
    int c = c0 + kk, t = t0 + tt;
    if (c < C_IN && t < T_FR) {
      size_t m = (size_t)b * T_FR + t;
      A[m * KPAD + c]        = f2b(tr[kk][tt]);   // real-part rows of basis
      A[m * KPAD + C_IN + c] = f2b(ti[kk][tt]);   // imag-part rows
    }
  }
}

// ---------------------------------------------------------------------------
// Transpose inverse_basis [C2, NFFT] fp32 -> Wt [NFFT, KPAD] bf16 (c-contiguous).
__global__ void build_Wt(const float* __restrict__ W, unsigned short* __restrict__ Wt) {
  __shared__ float tile[64][65];
  const int tid = threadIdx.x;
  const int n0 = blockIdx.x * 64;
  const int c0 = blockIdx.y * 64;
#pragma unroll
  for (int pass = 0; pass < 16; ++pass) {
    int idx = pass * 256 + tid;
    int nn = idx & 63, cc = idx >> 6;
    int c = c0 + cc;
    tile[cc][nn] = (c < C2) ? W[(size_t)c * NFFT + n0 + nn] : 0.f;
  }
  __syncthreads();
#pragma unroll
  for (int pass = 0; pass < 16; ++pass) {
    int idx = pass * 256 + tid;
    int cc = idx & 63, nn = idx >> 6;
    int c = c0 + cc;
    if (c < C2) Wt[(size_t)(n0 + nn) * KPAD + c] = f2b(tile[cc][nn]);
  }
}

// ---------------------------------------------------------------------------
// m97-style bf16 MFMA GEMM: C[m,n] = sum_k A[m,k]*Wt[n,k].
// 128x128 tile per 256-thread block (4 waves, 2x2, 64x64 each, 4x4 MFMA grid),
// BK=32, global_load_lds width-16 staging, 2 barriers per K-iteration.
__device__ __forceinline__ void async16(void* lds, const void* g) {
  __builtin_amdgcn_global_load_lds(
      (const __attribute__((address_space(1))) void*)g,
      (__attribute__((address_space(3))) void*)lds, 16, 0, 0);
}

__global__ __launch_bounds__(256) void gemm_bt(const unsigned short* __restrict__ A,
                                               const unsigned short* __restrict__ Bm,
                                               unsigned short* __restrict__ Cf) {
  __shared__ unsigned short As[128 * 32];
  __shared__ unsigned short Bs[128 * 32];
  const int tid = threadIdx.x;
  const int lane = tid & 63, w = tid >> 6;
  const int m0 = blockIdx.y * 128, n0 = blockIdx.x * 128;
  const int wm = (w & 1) * 64, wn = (w >> 1) * 64;
  const int r = lane & 15, q = lane >> 4;
  f32x4 acc[4][4] = {};

  for (int k0 = 0; k0 < KPAD; k0 += 32) {
    __syncthreads();   // previous compute done before overwriting LDS
#pragma unroll
    for (int iss = 0; iss < 2; ++iss) {
      int slot = iss * 256 + w * 64 + lane;     // 512 slots x 16B per operand
      int row = slot >> 2, kg = slot & 3;       // 4 x 16B per 32-elem row
      async16(&As[(size_t)(iss * 256 + w * 64) * 8],
              &A[(size_t)(m0 + row) * KPAD + k0 + kg * 8]);
      async16(&Bs[(size_t)(iss * 256 + w * 64) * 8],
              &Bm[(size_t)(n0 + row) * KPAD + k0 + kg * 8]);
    }
    __syncthreads();   // staging visible (vmcnt drained by barrier)

    bf16x8 av[4], bv[4];
#pragma unroll
    for (int i = 0; i < 4; ++i)
      av[i] = *(const bf16x8*)&As[(wm + i * 16 + r) * 32 + q * 8];
#pragma unroll
    for (int j = 0; j < 4; ++j)
      bv[j] = *(const bf16x8*)&Bs[(wn + j * 16 + r) * 32 + q * 8];
#pragma unroll
    for (int i = 0; i < 4; ++i)
#pragma unroll
      for (int j = 0; j < 4; ++j)
        acc[i][j] = __builtin_amdgcn_mfma_f32_16x16x32_bf16(av[i], bv[j], acc[i][j], 0, 0, 0);
  }

  // Epilogue: C/D layout col=lane&15, row=(lane>>4)*4+reg  (m89-verified)
#pragma unroll
  for (int i = 0; i < 4; ++i)
#pragma unroll
    for (int j = 0; j < 4; ++j)
#pragma unroll
      for (int rr = 0; rr < 4; ++rr) {
        int row = m0 + wm + i * 16 + q * 4 + rr;
        int col = n0 + wn + j * 16 + r;
        Cf[(size_t)row * NFFT + col] = f2b(acc[i][j][rr]);
      }
}

// ---------------------------------------------------------------------------
// Overlap-add + window_sum_inv + slice.  out[b,p] = wsi[s] * sum_t Fr[b,t,s-t*HOP],
// s = NFFT/2 + p, at most 4 overlapping frames.
__global__ void ola(const unsigned short* __restrict__ Fr, const float* __restrict__ wsi,
                    float* __restrict__ out, int length) {
  int p = blockIdx.x * 256 + threadIdx.x;
  int b = blockIdx.y;
  if (p >= length) return;
  int s = (NFFT / 2) + p;
  int tlo = (s - (NFFT - HOPSZ) - (HOPSZ - 1) - 1 + HOPSZ) >> 10;  // = (s-3072)>>10
  tlo = (s - 3072) >> 10;
  tlo = tlo < 0 ? 0 : tlo;
  int thi = s >> 10;
  thi = thi > (T_FR - 1) ? (T_FR - 1) : thi;
  float acc = 0.f;
  for (int t = tlo; t <= thi; ++t) {
    int k = s - (t << 10);
    acc += b2f(Fr[((size_t)(b * T_FR + t)) * NFFT + k]);
  }
  out[(size_t)b * length + p] = acc * wsi[s];
}

// ---------------------------------------------------------------------------
extern "C" void kernel_launch(void* const* d_in, const int* in_sizes, int n_in,
                              void* d_out, int out_size, void* d_ws, size_t ws_size,
                              hipStream_t stream) {
  const float* re  = (const float*)d_in[0];
  const float* im  = (const float*)d_in[1];
  const float* W   = (const float*)d_in[2];
  const float* wsi = (const float*)d_in[3];
  float* out = (float*)d_out;
  const int length = out_size / B_SZ;   // 352800

  // Workspace layout (80.1 MB total):
  unsigned short* A  = (unsigned short*)d_ws;                 // [MPAD x KPAD] bf16
  unsigned short* Wt = A + (size_t)MPAD * KPAD;               // [NFFT x KPAD] bf16
  unsigned short* Fr = Wt + (size_t)NFFT * KPAD;              // [MPAD x NFFT] bf16

  size_t zero16 = ((size_t)(MPAD + NFFT) * KPAD * 2) / 16;    // A+Wt bytes /16
  zero_ws<<<dim3((unsigned)((zero16 + 255) / 256)), 256, 0, stream>>>((uint4*)d_ws, (int)zero16);
  build_A<<<dim3((T_FR + 63) / 64, (C_IN + 63) / 64, B_SZ), 256, 0, stream>>>(re, im, A);
  build_Wt<<<dim3(NFFT / 64, (C2 + 63) / 64), 256, 0, stream>>>(W, Wt);
  gemm_bt<<<dim3(NFFT / 128, MPAD / 128), 256, 0, stream>>>(A, Wt, Fr);
  ola<<<dim3((length + 255) / 256, B_SZ), 256, 0, stream>>>(Fr, wsi, out, length);
}

// Round 2
// 241.827 us; speedup vs baseline: 1.3224x; 1.3224x over previous
//
#include <hip/hip_runtime.h>
#include <cstdint>
#include <cstddef>

// Problem constants (fixed by the reference file)
#define B_SZ  8
#define C_IN  2049          // N_FFT/2+1 = K (real half-spectrum)
#define T_FR  345           // MAX_FRAMES
#define NFFT  4096
#define HOPSZ 1024
#define KP2   2080          // 2049 padded to multiple of 32
#define NCOL  2049          // output columns n' in [0,2048]
#define NP2   2176          // 2049 padded to multiple of 128
#define MROWS 2760          // B_SZ*T_FR
#define MPAD  2816          // padded to multiple of 128

typedef __bf16 bf16x8 __attribute__((ext_vector_type(8)));
typedef float f32x4 __attribute__((ext_vector_type(4)));

__device__ __forceinline__ unsigned short f2b(float f) {
  union { float f; unsigned int u; } v; v.f = f;
  unsigned int r = v.u + 0x7fffu + ((v.u >> 16) & 1u);  // RNE to bf16
  return (unsigned short)(r >> 16);
}
__device__ __forceinline__ float b2f(unsigned short h) {
  union { unsigned int u; float f; } v; v.u = ((unsigned int)h) << 16;
  return v.f;
}

// ---------------------------------------------------------------------------
// Build A1[m,k]=mag*cos(phase), A2[m,k]=mag*sin(phase) (bf16, [MPAD x KP2],
// k-contiguous) from real/imag [B, C_IN, T_FR] via LDS tile transpose.
// Pad rows/cols are left poisoned: B's pad-k columns are exact zeros, and
// pad-m / pad-n' outputs are never read, so poison (finite bf16) is harmless.
__global__ void build_A(const float* __restrict__ re, const float* __restrict__ im,
                        unsigned short* __restrict__ A1, unsigned short* __restrict__ A2) {
  __shared__ float tr[64][65];
  __shared__ float ti[64][65];
  const int tid = threadIdx.x;
  const int t0 = blockIdx.x * 64;
  const int c0 = blockIdx.y * 64;
  const int b  = blockIdx.z;
#pragma unroll
  for (int pass = 0; pass < 16; ++pass) {
    int idx = pass * 256 + tid;
    int tt = idx & 63, cc = idx >> 6;
    int c = c0 + cc, t = t0 + tt;
    float rp = 0.f, ip = 0.f;
    if (c < C_IN && t < T_FR) {
      size_t off = ((size_t)b * C_IN + c) * T_FR + t;
      float r = re[off], i = im[off];
      float x   = r + 1.1920929e-7f;           // real + eps (phase arg)
      float mag = sqrtf(r * r + i * i);
      float h2  = sqrtf(x * x + i * i);
      float inv = (h2 > 0.f) ? (mag / h2) : 0.f;
      rp = x * inv;                             // mag*cos(phase)
      ip = i * inv;                             // mag*sin(phase)
    }
    tr[cc][tt] = rp;
    ti[cc][tt] = ip;
  }
  __syncthreads();
#pragma unroll
  for (int pass = 0; pass < 16; ++pass) {
    int idx = pass * 256 + tid;
    int kk = idx & 63, tt = idx >> 6;
    int c = c0 + kk, t = t0 + tt;
    if (c < C_IN && t < T_FR) {
      size_t m = (size_t)b * T_FR + t;
      A1[m * KP2 + c] = f2b(tr[kk][tt]);
      A2[m * KP2 + c] = f2b(ti[kk][tt]);
    }
  }
}

// ---------------------------------------------------------------------------
// Build the analytic transposed bases (no global reads, symmetric in k<->n'):
//   B1[n',k] = scale_c(k) * cos(2*pi*k*n'/N)
//   B2[n',k] = scale_s(k) * sin(2*pi*k*n'/N)
// scale_c: 1/256 at k=0,2048; 1/128 for 1..2047,2048<k<2049?; 0 for pad k>=2049
// scale_s: 1/128 for k in [1,2047]; 0 at k=0,2048 (zero-norm rows) and pad.
__global__ void build_B(unsigned short* __restrict__ B1, unsigned short* __restrict__ B2) {
  int idx = blockIdx.x * 256 + threadIdx.x;
  if (idx >= NP2 * KP2) return;
  int k = idx % KP2;
  int n = idx / KP2;
  int prod = (k * n) & (NFFT - 1);           // exact arg reduction mod 4096
  float th = (float)prod * 1.5339807879e-3f; // 2*pi/4096
  float sv, cv;
  __sincosf(th, &sv, &cv);
  float sc_c = (k < NCOL) ? ((k == 0 || k == 2048) ? 0.00390625f : 0.0078125f) : 0.f;
  float sc_s = (k >= 1 && k <= 2047) ? 0.0078125f : 0.f;
  if (blockIdx.y == 0) B1[idx] = f2b(cv * sc_c);
  else                 B2[idx] = f2b(sv * sc_s);
}

// ---------------------------------------------------------------------------
// m97-style bf16 MFMA GEMM: C[m,n'] = sum_k A[m,k]*Bt[n',k].
// 128x128 tile / 256 threads, BK=32, global_load_lds width-16 staging.
// grid.z selects (A1,B1)->C or (A2,B2)->S.
__device__ __forceinline__ void async16(void* lds, const void* g) {
  __builtin_amdgcn_global_load_lds(
      (const __attribute__((address_space(1))) void*)g,
      (__attribute__((address_space(3))) void*)lds, 16, 0, 0);
}

__global__ __launch_bounds__(256) void gemm_bt(const unsigned short* __restrict__ A1,
                                               const unsigned short* __restrict__ A2,
                                               const unsigned short* __restrict__ B1,
                                               const unsigned short* __restrict__ B2,
                                               unsigned short* __restrict__ Cm,
                                               unsigned short* __restrict__ Sm) {
  __shared__ unsigned short As[128 * 32];
  __shared__ unsigned short Bs[128 * 32];
  const unsigned short* __restrict__ A  = blockIdx.z ? A2 : A1;
  const unsigned short* __restrict__ Bm = blockIdx.z ? B2 : B1;
  unsigned short* __restrict__ Cf       = blockIdx.z ? Sm : Cm;
  const int tid = threadIdx.x;
  const int lane = tid & 63, w = tid >> 6;
  const int m0 = blockIdx.y * 128, n0 = blockIdx.x * 128;
  const int wm = (w & 1) * 64, wn = (w >> 1) * 64;
  const int r = lane & 15, q = lane >> 4;
  f32x4 acc[4][4] = {};

  for (int k0 = 0; k0 < KP2; k0 += 32) {
    __syncthreads();   // previous compute done before overwriting LDS
#pragma unroll
    for (int iss = 0; iss < 2; ++iss) {
      int slot = iss * 256 + w * 64 + lane;     // 512 slots x 16B per operand
      int row = slot >> 2, kg = slot & 3;       // 4 x 16B per 32-elem row
      async16(&As[(size_t)(iss * 256 + w * 64) * 8],
              &A[(size_t)(m0 + row) * KP2 + k0 + kg * 8]);
      async16(&Bs[(size_t)(iss * 256 + w * 64) * 8],
              &Bm[(size_t)(n0 + row) * KP2 + k0 + kg * 8]);
    }
    __syncthreads();   // staging visible

    bf16x8 av[4], bv[4];
#pragma unroll
    for (int i = 0; i < 4; ++i)
      av[i] = *(const bf16x8*)&As[(wm + i * 16 + r) * 32 + q * 8];
#pragma unroll
    for (int j = 0; j < 4; ++j)
      bv[j] = *(const bf16x8*)&Bs[(wn + j * 16 + r) * 32 + q * 8];
#pragma unroll
    for (int i = 0; i < 4; ++i)
#pragma unroll
      for (int j = 0; j < 4; ++j)
        acc[i][j] = __builtin_amdgcn_mfma_f32_16x16x32_bf16(av[i], bv[j], acc[i][j], 0, 0, 0);
  }

  // Epilogue: C/D layout col=lane&15, row=(lane>>4)*4+reg  (m89-verified)
#pragma unroll
  for (int i = 0; i < 4; ++i)
#pragma unroll
    for (int j = 0; j < 4; ++j)
#pragma unroll
      for (int rr = 0; rr < 4; ++rr) {
        int row = m0 + wm + i * 16 + q * 4 + rr;
        int col = n0 + wn + j * 16 + r;
        Cf[(size_t)row * NP2 + col] = f2b(acc[i][j][rr]);
      }
}

// ---------------------------------------------------------------------------
// Overlap-add + analytic window + window_sum_inv + slice.
// frame value at (t, n): n<=2048: win[n]*(C[t,n]-S[t,n]);
//                        n> 2048: win[n]*(C[t,4096-n]+S[t,4096-n]).
__global__ void ola(const unsigned short* __restrict__ Cm, const unsigned short* __restrict__ Sm,
                    const float* __restrict__ wsi, float* __restrict__ out, int length) {
  int p = blockIdx.x * 256 + threadIdx.x;
  int b = blockIdx.y;
  if (p >= length) return;
  int s = (NFFT / 2) + p;
  int tlo = (s - 3072) >> 10;
  tlo = tlo < 0 ? 0 : tlo;
  int thi = s >> 10;
  thi = thi > (T_FR - 1) ? (T_FR - 1) : thi;
  float acc = 0.f;
  for (int t = tlo; t <= thi; ++t) {
    int n = s - (t << 10);
    int m = b * T_FR + t;
    int np = (n <= 2048) ? n : (NFFT - n);
    float cv = b2f(Cm[(size_t)m * NP2 + np]);
    float sv = b2f(Sm[(size_t)m * NP2 + np]);
    float fr = (n <= 2048) ? (cv - sv) : (cv + sv);
    float win = 0.5f - 0.5f * __cosf((float)n * 1.5339807879e-3f);
    acc += win * fr;
  }
  out[(size_t)b * length + p] = acc * wsi[s];
}

// ---------------------------------------------------------------------------
extern "C" void kernel_launch(void* const* d_in, const int* in_sizes, int n_in,
                              void* d_out, int out_size, void* d_ws, size_t ws_size,
                              hipStream_t stream) {
  const float* re  = (const float*)d_in[0];
  const float* im  = (const float*)d_in[1];
  // d_in[2] (inverse_basis) no longer needed — basis is analytic.
  const float* wsi = (const float*)d_in[3];
  float* out = (float*)d_out;
  const int length = out_size / B_SZ;   // 352800

  // Workspace layout (66.0 MB total, all bf16/ushort):
  unsigned short* A1 = (unsigned short*)d_ws;                 // [MPAD x KP2]
  unsigned short* A2 = A1 + (size_t)MPAD * KP2;
  unsigned short* B1 = A2 + (size_t)MPAD * KP2;               // [NP2 x KP2]
  unsigned short* B2 = B1 + (size_t)NP2 * KP2;
  unsigned short* Cm = B2 + (size_t)NP2 * KP2;                // [MPAD x NP2]
  unsigned short* Sm = Cm + (size_t)MPAD * NP2;

  build_A<<<dim3((T_FR + 63) / 64, (C_IN + 63) / 64, B_SZ), 256, 0, stream>>>(re, im, A1, A2);
  build_B<<<dim3((NP2 * KP2 + 255) / 256, 2), 256, 0, stream>>>(B1, B2);
  gemm_bt<<<dim3(NP2 / 128, MPAD / 128, 2), 256, 0, stream>>>(A1, A2, B1, B2, Cm, Sm);
  ola<<<dim3((length + 255) / 256, B_SZ), 256, 0, stream>>>(Cm, Sm, wsi, out, length);
}

// Round 3
// 197.393 us; speedup vs baseline: 1.6200x; 1.2251x over previous
//
#include <hip/hip_runtime.h>
#include <cstdint>
#include <cstddef>

// Problem constants (fixed by the reference file)
#define B_SZ  8
#define C_IN  2049          // N_FFT/2+1
#define T_FR  345           // MAX_FRAMES
#define NFFT  4096
#define HOPSZ 1024
#define MFR   2760          // B_SZ*T_FR frames
#define TW    1.5339807878856412e-3f   // 2*pi/4096

typedef float f4 __attribute__((ext_vector_type(4)));

__device__ __forceinline__ unsigned short f2b(float f) {
  union { float f; unsigned int u; } v; v.f = f;
  unsigned int r = v.u + 0x7fffu + ((v.u >> 16) & 1u);  // RNE to bf16
  return (unsigned short)(r >> 16);
}
__device__ __forceinline__ float b2f(unsigned int h) {
  union { unsigned int u; float f; } v; v.u = h << 16;
  return v.f;
}

// ---------------------------------------------------------------------------
// trans: [B, C_IN, T_FR] re/im fp32 -> spec[(b*T+t)*2049 + c] packed bf16 pair
// (re in low 16, im in high 16). LDS 64x64 tile transpose; mag/phase
// recombination: r' = mag*(r+eps)/hyp, i' = mag*i/hyp.
__global__ void trans(const float* __restrict__ re, const float* __restrict__ im,
                      unsigned int* __restrict__ spec) {
  __shared__ float tr[64][65];
  __shared__ float ti[64][65];
  const int tid = threadIdx.x;
  const int t0 = blockIdx.x * 64;
  const int c0 = blockIdx.y * 64;
  const int b  = blockIdx.z;
#pragma unroll
  for (int pass = 0; pass < 16; ++pass) {
    int idx = pass * 256 + tid;
    int tt = idx & 63, cc = idx >> 6;
    int c = c0 + cc, t = t0 + tt;
    float rp = 0.f, ip = 0.f;
    if (c < C_IN && t < T_FR) {
      size_t off = ((size_t)b * C_IN + c) * T_FR + t;
      float r = re[off], i = im[off];
      float x   = r + 1.1920929e-7f;           // real + eps (phase arg)
      float mag = sqrtf(r * r + i * i);
      float h2  = sqrtf(x * x + i * i);
      float inv = (h2 > 0.f) ? (mag / h2) : 0.f;
      rp = x * inv;                             // mag*cos(phase)
      ip = i * inv;                             // mag*sin(phase)
    }
    tr[cc][tt] = rp;
    ti[cc][tt] = ip;
  }
  __syncthreads();
#pragma unroll
  for (int pass = 0; pass < 16; ++pass) {
    int idx = pass * 256 + tid;
    int kk = idx & 63, tt = idx >> 6;
    int c = c0 + kk, t = t0 + tt;
    if (c < C_IN && t < T_FR) {
      size_t mrow = (size_t)b * T_FR + t;
      unsigned int pk = ((unsigned int)f2b(ti[kk][tt]) << 16) | f2b(tr[kk][tt]);
      spec[mrow * C_IN + c] = pk;
    }
  }
}

// ---------------------------------------------------------------------------
// Stockham radix-4 DIF inverse-FFT stage (autosort, natural-order output).
// Element-index identities (4LM = 4096, idx4 = 4*tid + p, p in [0,4)):
//   reads : x[idx4 + 1024*q]              -> float4 index tid + 256*q (all stages)
//   writes: y[k0 + M*(4j+q)], j=idx4/M    -> float4 index (k0>>2)+M*j+(M>>2)*q (M>=4)
// Inverse butterfly: t0=a+c, t1=a-c, t2=b+d, t3=+i(b-d);
//   y0=t0+t2, y1=W^j(t1+t3), y2=W^2j(t0-t2), y3=W^3j(t1-t3), W=cis(+2*pi*M/4096).
// Verified by hand at N=4 (y[q]=IDFT4[q]).
template<int M, int L2M>
__device__ __forceinline__ void fft_stage(const f4* __restrict__ sr, const f4* __restrict__ si,
                                          f4* __restrict__ dr, f4* __restrict__ di, int tid) {
  f4 ar = sr[tid],       ai = si[tid];
  f4 br = sr[tid + 256], bi = si[tid + 256];
  f4 cr = sr[tid + 512], ci = si[tid + 512];
  f4 er = sr[tid + 768], ei = si[tid + 768];
  f4 t0r = ar + cr, t0i = ai + ci;
  f4 t1r = ar - cr, t1i = ai - ci;
  f4 t2r = br + er, t2i = bi + ei;
  f4 t3r = ei - bi, t3i = br - er;          // +i*(b-d)
  f4 y0r = t0r + t2r, y0i = t0i + t2i;
  f4 u1r = t1r + t3r, u1i = t1i + t3i;
  f4 u2r = t0r - t2r, u2i = t0i - t2i;
  f4 u3r = t1r - t3r, u3i = t1i - t3i;
  const int base = tid << 2;
  if (M == 1) {
    // j varies per p; outputs y[4j+q] -> one float4 per p (components = q).
#pragma unroll
    for (int p = 0; p < 4; ++p) {
      int j = base + p;
      float s1, c1; __sincosf((float)j * TW, &s1, &c1);
      float c2 = c1 * c1 - s1 * s1, s2 = 2.f * c1 * s1;
      float c3 = c2 * c1 - s2 * s1, s3 = s2 * c1 + c2 * s1;
      f4 o, oi;
      o.x  = y0r[p];
      o.y  = c1 * u1r[p] - s1 * u1i[p];
      o.z  = c2 * u2r[p] - s2 * u2i[p];
      o.w  = c3 * u3r[p] - s3 * u3i[p];
      oi.x = y0i[p];
      oi.y = c1 * u1i[p] + s1 * u1r[p];
      oi.z = c2 * u2i[p] + s2 * u2r[p];
      oi.w = c3 * u3i[p] + s3 * u3r[p];
      dr[j] = o; di[j] = oi;
    }
  } else {
    const int j  = base >> L2M;               // same for all 4 p's (4 | M)
    const int kb = (base & (M - 1)) >> 2;
    float s1, c1; __sincosf((float)(j * M) * TW, &s1, &c1);
    float c2 = c1 * c1 - s1 * s1, s2 = 2.f * c1 * s1;
    float c3 = c2 * c1 - s2 * s1, s3 = s2 * c1 + c2 * s1;
    const int wb = kb + M * j;
    const int Q  = M >> 2;
    dr[wb]         = y0r;                      di[wb]         = y0i;
    dr[wb + Q]     = c1 * u1r - s1 * u1i;      di[wb + Q]     = c1 * u1i + s1 * u1r;
    dr[wb + 2 * Q] = c2 * u2r - s2 * u2i;      di[wb + 2 * Q] = c2 * u2i + s2 * u2r;
    dr[wb + 3 * Q] = c3 * u3r - s3 * u3i;      di[wb + 3 * Q] = c3 * u3i + s3 * u3r;
  }
}

// ---------------------------------------------------------------------------
// One 4096-point inverse FFT per block (frame m). Hermitian-extend the 2049
// half-spectrum, 6 Stockham radix-4 stages, take Re, fold in hann window and
// the 1/256 scale, store bf16 frames.  (Imag parts at k=0/2048 ride along in
// im[] only — Re() drops them, matching the reference's zero-norm sin rows.)
__global__ __launch_bounds__(256) void ifft_frames(const unsigned int* __restrict__ spec,
                                                   unsigned short* __restrict__ Fr) {
  __shared__ f4 B0r[1024], B0i[1024], B1r[1024], B1i[1024];   // 64 KiB ping-pong
  float* r0 = (float*)B0r;
  float* i0 = (float*)B0i;
  const int m = blockIdx.x, tid = threadIdx.x;
  const unsigned int* sp = spec + (size_t)m * C_IN;
#pragma unroll
  for (int p = 0; p < 8; ++p) {
    int k = p * 256 + tid;                    // k in [0, 2047]
    unsigned int v = sp[k];
    float a = b2f(v & 0xffffu), b = b2f(v >> 16);
    r0[k] = a; i0[k] = b;
    if (k >= 1) { r0[4096 - k] = a; i0[4096 - k] = -b; }   // conj mirror
  }
  if (tid == 0) {                             // Nyquist, self-mirror: write once
    unsigned int v = sp[2048];
    r0[2048] = b2f(v & 0xffffu); i0[2048] = b2f(v >> 16);
  }
  __syncthreads();
  fft_stage<1,    0>(B0r, B0i, B1r, B1i, tid); __syncthreads();
  fft_stage<4,    2>(B1r, B1i, B0r, B0i, tid); __syncthreads();
  fft_stage<16,   4>(B0r, B0i, B1r, B1i, tid); __syncthreads();
  fft_stage<64,   6>(B1r, B1i, B0r, B0i, tid); __syncthreads();
  fft_stage<256,  8>(B0r, B0i, B1r, B1i, tid); __syncthreads();
  fft_stage<1024,10>(B1r, B1i, B0r, B0i, tid); __syncthreads();
  unsigned short* dst = Fr + (size_t)m * NFFT;
#pragma unroll
  for (int p = 0; p < 16; ++p) {
    int n = p * 256 + tid;
    float w = (0.5f - 0.5f * __cosf((float)n * TW)) * 0.00390625f;  // win/256
    dst[n] = f2b(r0[n] * w);
  }
}

// ---------------------------------------------------------------------------
// Overlap-add gather + window_sum_inv + slice.  Window already in Fr.
__global__ void ola(const unsigned short* __restrict__ Fr, const float* __restrict__ wsi,
                    float* __restrict__ out, int length) {
  int p = blockIdx.x * 256 + threadIdx.x;
  int b = blockIdx.y;
  if (p >= length) return;
  int s = (NFFT / 2) + p;
  int tlo = (s - 3072) >> 10;
  tlo = tlo < 0 ? 0 : tlo;
  int thi = s >> 10;
  thi = thi > (T_FR - 1) ? (T_FR - 1) : thi;
  float acc = 0.f;
  for (int t = tlo; t <= thi; ++t) {
    int n = s - (t << 10);
    acc += b2f((unsigned int)Fr[((size_t)(b * T_FR + t)) * NFFT + n]);
  }
  out[(size_t)b * length + p] = acc * wsi[s];
}

// ---------------------------------------------------------------------------
extern "C" void kernel_launch(void* const* d_in, const int* in_sizes, int n_in,
                              void* d_out, int out_size, void* d_ws, size_t ws_size,
                              hipStream_t stream) {
  const float* re  = (const float*)d_in[0];
  const float* im  = (const float*)d_in[1];
  // d_in[2] (inverse_basis) unused — spectral identity HW-verified in round 2.
  const float* wsi = (const float*)d_in[3];
  float* out = (float*)d_out;
  const int length = out_size / B_SZ;   // 352800

  // Workspace (45.2 MB): spec packed-bf16 [MFR x 2049], Fr bf16 [MFR x 4096].
  unsigned int*   spec = (unsigned int*)d_ws;
  unsigned short* Fr   = (unsigned short*)(spec + (size_t)MFR * C_IN);

  trans<<<dim3((T_FR + 63) / 64, (C_IN + 63) / 64, B_SZ), 256, 0, stream>>>(re, im, spec);
  ifft_frames<<<dim3(MFR), 256, 0, stream>>>(spec, Fr);
  ola<<<dim3((length + 255) / 256, B_SZ), 256, 0, stream>>>(Fr, wsi, out, length);
}

// Round 4
// 181.328 us; speedup vs baseline: 1.7635x; 1.0886x over previous
//
#include <hip/hip_runtime.h>
#include <cstdint>
#include <cstddef>

// Problem constants (fixed by the reference file)
#define B_SZ  8
#define C_IN  2049          // N_FFT/2+1
#define T_FR  345           // MAX_FRAMES
#define NFFT  4096
#define HOPSZ 1024
#define MFR   2760          // B_SZ*T_FR frames
#define NPAIR 173           // ceil(345/2) frame-pairs per batch
#define TW    1.5339807878856412e-3f   // 2*pi/4096

typedef float f4 __attribute__((ext_vector_type(4)));

__device__ __forceinline__ unsigned short f2b(float f) {
  union { float f; unsigned int u; } v; v.f = f;
  unsigned int r = v.u + 0x7fffu + ((v.u >> 16) & 1u);  // RNE to bf16
  return (unsigned short)(r >> 16);
}
__device__ __forceinline__ float b2f(unsigned int h) {
  union { unsigned int u; float f; } v; v.u = h << 16;
  return v.f;
}

// ---------------------------------------------------------------------------
// trans: [B, C_IN, T_FR] re/im fp32 -> spec[(b*T+t)*2049 + c] packed bf16 pair
// (re low 16, im high 16). LDS 64x64 tile transpose; fast-math recombine:
// r' = x*sqrt(r^2+i^2)*rsqrt(x^2+i^2), x = r+eps  (bf16 target, approx ok).
__global__ void trans(const float* __restrict__ re, const float* __restrict__ im,
                      unsigned int* __restrict__ spec) {
  __shared__ float tr[64][65];
  __shared__ float ti[64][65];
  const int tid = threadIdx.x;
  const int t0 = blockIdx.x * 64;
  const int c0 = blockIdx.y * 64;
  const int b  = blockIdx.z;
#pragma unroll
  for (int pass = 0; pass < 16; ++pass) {
    int idx = pass * 256 + tid;
    int tt = idx & 63, cc = idx >> 6;
    int c = c0 + cc, t = t0 + tt;
    float rp = 0.f, ip = 0.f;
    if (c < C_IN && t < T_FR) {
      size_t off = ((size_t)b * C_IN + c) * T_FR + t;
      float r = re[off], i = im[off];
      float x  = r + 1.1920929e-7f;            // real + eps (phase arg)
      float r2 = r * r + i * i;
      float h2 = fmaxf(x * x + i * i, 1e-35f);
      float inv = __builtin_amdgcn_sqrtf(r2) * __builtin_amdgcn_rsqf(h2);
      rp = x * inv;                             // mag*cos(phase)
      ip = i * inv;                             // mag*sin(phase)
    }
    tr[cc][tt] = rp;
    ti[cc][tt] = ip;
  }
  __syncthreads();
#pragma unroll
  for (int pass = 0; pass < 16; ++pass) {
    int idx = pass * 256 + tid;
    int kk = idx & 63, tt = idx >> 6;
    int c = c0 + kk, t = t0 + tt;
    if (c < C_IN && t < T_FR) {
      size_t mrow = (size_t)b * T_FR + t;
      unsigned int pk = ((unsigned int)f2b(ti[kk][tt]) << 16) | f2b(tr[kk][tt]);
      spec[mrow * C_IN + c] = pk;
    }
  }
}

// ---------------------------------------------------------------------------
// Stockham radix-4 DIF inverse-FFT stage (autosort, natural-order output).
// Reads at float4 index tid+256q every stage; writes per the Stockham map.
// Inverse butterfly: t0=a+c, t1=a-c, t2=b+d, t3=+i(b-d);
//   y0=t0+t2, y1=W^j(t1+t3), y2=W^2j(t0-t2), y3=W^3j(t1-t3), W=cis(+2*pi*M/4096).
// HW-verified in round 3.
template<int M, int L2M>
__device__ __forceinline__ void fft_stage(const f4* __restrict__ sr, const f4* __restrict__ si,
                                          f4* __restrict__ dr, f4* __restrict__ di, int tid) {
  f4 ar = sr[tid],       ai = si[tid];
  f4 br = sr[tid + 256], bi = si[tid + 256];
  f4 cr = sr[tid + 512], ci = si[tid + 512];
  f4 er = sr[tid + 768], ei = si[tid + 768];
  f4 t0r = ar + cr, t0i = ai + ci;
  f4 t1r = ar - cr, t1i = ai - ci;
  f4 t2r = br + er, t2i = bi + ei;
  f4 t3r = ei - bi, t3i = br - er;          // +i*(b-d)
  f4 y0r = t0r + t2r, y0i = t0i + t2i;
  f4 u1r = t1r + t3r, u1i = t1i + t3i;
  f4 u2r = t0r - t2r, u2i = t0i - t2i;
  f4 u3r = t1r - t3r, u3i = t1i - t3i;
  const int base = tid << 2;
  if (M == 1) {
#pragma unroll
    for (int p = 0; p < 4; ++p) {
      int j = base + p;
      float s1, c1; __sincosf((float)j * TW, &s1, &c1);
      float c2 = c1 * c1 - s1 * s1, s2 = 2.f * c1 * s1;
      float c3 = c2 * c1 - s2 * s1, s3 = s2 * c1 + c2 * s1;
      f4 o, oi;
      o.x  = y0r[p];
      o.y  = c1 * u1r[p] - s1 * u1i[p];
      o.z  = c2 * u2r[p] - s2 * u2i[p];
      o.w  = c3 * u3r[p] - s3 * u3i[p];
      oi.x = y0i[p];
      oi.y = c1 * u1i[p] + s1 * u1r[p];
      oi.z = c2 * u2i[p] + s2 * u2r[p];
      oi.w = c3 * u3i[p] + s3 * u3r[p];
      dr[j] = o; di[j] = oi;
    }
  } else {
    const int j  = base >> L2M;
    const int kb = (base & (M - 1)) >> 2;
    float s1, c1; __sincosf((float)(j * M) * TW, &s1, &c1);
    float c2 = c1 * c1 - s1 * s1, s2 = 2.f * c1 * s1;
    float c3 = c2 * c1 - s2 * s1, s3 = s2 * c1 + c2 * s1;
    const int wb = kb + M * j;
    const int Q  = M >> 2;
    dr[wb]         = y0r;                      di[wb]         = y0i;
    dr[wb + Q]     = c1 * u1r - s1 * u1i;      di[wb + Q]     = c1 * u1i + s1 * u1r;
    dr[wb + 2 * Q] = c2 * u2r - s2 * u2i;      di[wb + 2 * Q] = c2 * u2i + s2 * u2r;
    dr[wb + 3 * Q] = c3 * u3r - s3 * u3i;      di[wb + 3 * Q] = c3 * u3i + s3 * u3r;
  }
}

// ---------------------------------------------------------------------------
// Real-pair IFFT: one 4096-pt complex IFFT yields TWO real frames.
// Z[k] = Y_a[k] + i*Y_b[k] with both Y hermitian-extended (imag at DC/Nyquist
// dropped, matching the reference's zero-norm sin rows):
//   k in [1,2047]: Z[k]      = (ar - bi) + i(ai + br)
//                  Z[4096-k] = (ar + bi) + i(br - ai)
//   Z[0] = ar0 + i*br0,  Z[2048] = arN + i*brN
// After IFFT: frame a = Re, frame b = Im. Window*1/256 folded into the store.
__global__ __launch_bounds__(256) void ifft_frames(const unsigned int* __restrict__ spec,
                                                   unsigned short* __restrict__ Fr) {
  __shared__ f4 B0r[1024], B0i[1024], B1r[1024], B1i[1024];   // 64 KiB ping-pong
  float* r0 = (float*)B0r;
  float* i0 = (float*)B0i;
  const int tid = threadIdx.x;
  const int j = blockIdx.x, b = blockIdx.y;
  const int ta = b * T_FR + 2 * j;            // frame a (always valid)
  const bool hasb = (2 * j + 1) < T_FR;       // frame b exists (t=344 leftover)
  const unsigned int* spa = spec + (size_t)ta * C_IN;
  const unsigned int* spb = spa + C_IN;
#pragma unroll
  for (int p = 0; p < 8; ++p) {
    int k = p * 256 + tid;                    // k in [0, 2047]
    unsigned int va = spa[k];
    unsigned int vb = hasb ? spb[k] : 0u;
    float ar = b2f(va & 0xffffu), ai = b2f(va >> 16);
    float br = b2f(vb & 0xffffu), bi = b2f(vb >> 16);
    if (k == 0) {
      r0[0] = ar; i0[0] = br;                 // drop DC imag parts
    } else {
      r0[k] = ar - bi;        i0[k] = ai + br;
      r0[4096 - k] = ar + bi; i0[4096 - k] = br - ai;
    }
  }
  if (tid == 0) {                             // Nyquist (real parts only)
    unsigned int va = spa[2048];
    unsigned int vb = hasb ? spb[2048] : 0u;
    r0[2048] = b2f(va & 0xffffu);
    i0[2048] = b2f(vb & 0xffffu);
  }
  __syncthreads();
  fft_stage<1,    0>(B0r, B0i, B1r, B1i, tid); __syncthreads();
  fft_stage<4,    2>(B1r, B1i, B0r, B0i, tid); __syncthreads();
  fft_stage<16,   4>(B0r, B0i, B1r, B1i, tid); __syncthreads();
  fft_stage<64,   6>(B1r, B1i, B0r, B0i, tid); __syncthreads();
  fft_stage<256,  8>(B0r, B0i, B1r, B1i, tid); __syncthreads();
  fft_stage<1024,10>(B1r, B1i, B0r, B0i, tid); __syncthreads();
  unsigned int* da = (unsigned int*)(Fr + (size_t)ta * NFFT);
  unsigned int* db = (unsigned int*)(Fr + (size_t)(ta + 1) * NFFT);
#pragma unroll
  for (int p = 0; p < 8; ++p) {
    int n2 = p * 256 + tid;                   // packed-pair index, n = 2*n2
    int n = n2 * 2;
    float w0 = (0.5f - 0.5f * __cosf((float)n * TW)) * 0.00390625f;        // win/256
    float w1 = (0.5f - 0.5f * __cosf((float)(n + 1) * TW)) * 0.00390625f;
    da[n2] = ((unsigned int)f2b(r0[n + 1] * w1) << 16) | f2b(r0[n] * w0);
    if (hasb)
      db[n2] = ((unsigned int)f2b(i0[n + 1] * w1) << 16) | f2b(i0[n] * w0);
  }
}

// ---------------------------------------------------------------------------
// Overlap-add gather, x4 vectorized. Quads are 4-aligned and boundaries are at
// multiples of 1024, so all 4 outputs of a quad share the same tap range ->
// one ushort4 load per tap, float4 wsi load, float4 store.
__global__ void ola(const unsigned short* __restrict__ Fr, const float* __restrict__ wsi,
                    float* __restrict__ out, int length) {
  int q = blockIdx.x * 256 + threadIdx.x;
  int b = blockIdx.y;
  int p4 = q * 4;
  if (p4 >= length) return;
  int s0 = (NFFT / 2) + p4;
  int tlo = (s0 - 3072) >> 10;
  tlo = tlo < 0 ? 0 : tlo;
  int thi = s0 >> 10;
  thi = thi > (T_FR - 1) ? (T_FR - 1) : thi;
  float a0 = 0.f, a1 = 0.f, a2 = 0.f, a3 = 0.f;
  for (int t = tlo; t <= thi; ++t) {
    const unsigned short* fp = Fr + ((size_t)(b * T_FR + t)) * NFFT + (s0 - (t << 10));
    ushort4 v = *(const ushort4*)fp;          // 8B aligned: s0 % 4 == 0
    a0 += b2f(v.x); a1 += b2f(v.y); a2 += b2f(v.z); a3 += b2f(v.w);
  }
  float4 wv = *(const float4*)(wsi + s0);
  float4 o; o.x = a0 * wv.x; o.y = a1 * wv.y; o.z = a2 * wv.z; o.w = a3 * wv.w;
  *(float4*)(out + (size_t)b * length + p4) = o;
}

// ---------------------------------------------------------------------------
extern "C" void kernel_launch(void* const* d_in, const int* in_sizes, int n_in,
                              void* d_out, int out_size, void* d_ws, size_t ws_size,
                              hipStream_t stream) {
  const float* re  = (const float*)d_in[0];
  const float* im  = (const float*)d_in[1];
  // d_in[2] (inverse_basis) unused — spectral identity HW-verified in round 2/3.
  const float* wsi = (const float*)d_in[3];
  float* out = (float*)d_out;
  const int length = out_size / B_SZ;   // 352800

  // Workspace (45.2 MB): spec packed-bf16 [MFR x 2049], Fr bf16 [MFR x 4096].
  unsigned int*   spec = (unsigned int*)d_ws;
  unsigned short* Fr   = (unsigned short*)(spec + (size_t)MFR * C_IN);

  trans<<<dim3((T_FR + 63) / 64, (C_IN + 63) / 64, B_SZ), 256, 0, stream>>>(re, im, spec);
  ifft_frames<<<dim3(NPAIR, B_SZ), 256, 0, stream>>>(spec, Fr);
  ola<<<dim3((length / 4 + 255) / 256, B_SZ), 256, 0, stream>>>(Fr, wsi, out, length);
}